// Round 7
// baseline (400.671 us; speedup 1.0000x reference)
//
#include <hip/hip_runtime.h>
#include <stdint.h>
#include <math.h>

// Problem constants: B=16, H=W=56, HW=3136, pipeline 256 -> 64 -> 64 -> 256
#define HW 3136
#define NPIX 50176  // 16*3136

// ---------------------------------------------------------------------------
// MFMA types & helpers (gfx950 v_mfma_f32_16x16x32_bf16)
// Verified layouts: A[m=lane&15][k=quad*8+j]; B stored as B^T[n=lane&15][k];
// D col=lane&15, row=quad*4+reg.
// ---------------------------------------------------------------------------
typedef __attribute__((ext_vector_type(8))) short bf16x8;
typedef __attribute__((ext_vector_type(4))) float f32x4;
#define MFMA16(a, b, c) __builtin_amdgcn_mfma_f32_16x16x32_bf16(a, b, c, 0, 0, 0)

__device__ __forceinline__ unsigned short f2bf(float f) {  // RNE f32->bf16
  unsigned u = __float_as_uint(f);
  u = (u + 0x7fffu + ((u >> 16) & 1u)) >> 16;
  return (unsigned short)u;
}
__device__ __forceinline__ unsigned pk2(float a, float b) {
  return (unsigned)f2bf(a) | ((unsigned)f2bf(b) << 16);
}
__device__ __forceinline__ float bf2f(unsigned short h) {
  return __uint_as_float(((unsigned)h) << 16);
}

// ---------------------------------------------------------------------------
// threefry2x32 (Random123 / JAX-exact), host-side for key derivation
// ---------------------------------------------------------------------------
__host__ __device__ __forceinline__ uint32_t rotl32(uint32_t v, int r) {
  return (v << r) | (v >> (32 - r));
}

__host__ __device__ inline void threefry2x32(uint32_t k0, uint32_t k1,
                                             uint32_t x0, uint32_t x1,
                                             uint32_t& o0, uint32_t& o1) {
  uint32_t k2 = k0 ^ k1 ^ 0x1BD11BDAu;
  x0 += k0; x1 += k1;
  x0 += x1; x1 = rotl32(x1, 13); x1 ^= x0;
  x0 += x1; x1 = rotl32(x1, 15); x1 ^= x0;
  x0 += x1; x1 = rotl32(x1, 26); x1 ^= x0;
  x0 += x1; x1 = rotl32(x1, 6);  x1 ^= x0;
  x0 += k1; x1 += k2 + 1u;
  x0 += x1; x1 = rotl32(x1, 17); x1 ^= x0;
  x0 += x1; x1 = rotl32(x1, 29); x1 ^= x0;
  x0 += x1; x1 = rotl32(x1, 16); x1 ^= x0;
  x0 += x1; x1 = rotl32(x1, 24); x1 ^= x0;
  x0 += k2; x1 += k0 + 2u;
  x0 += x1; x1 = rotl32(x1, 13); x1 ^= x0;
  x0 += x1; x1 = rotl32(x1, 15); x1 ^= x0;
  x0 += x1; x1 = rotl32(x1, 26); x1 ^= x0;
  x0 += x1; x1 = rotl32(x1, 6);  x1 ^= x0;
  x0 += k0; x1 += k1 + 3u;
  x0 += x1; x1 = rotl32(x1, 17); x1 ^= x0;
  x0 += x1; x1 = rotl32(x1, 29); x1 ^= x0;
  x0 += x1; x1 = rotl32(x1, 16); x1 ^= x0;
  x0 += x1; x1 = rotl32(x1, 24); x1 ^= x0;
  x0 += k1; x1 += k2 + 4u;
  x0 += x1; x1 = rotl32(x1, 13); x1 ^= x0;
  x0 += x1; x1 = rotl32(x1, 15); x1 ^= x0;
  x0 += x1; x1 = rotl32(x1, 26); x1 ^= x0;
  x0 += x1; x1 = rotl32(x1, 6);  x1 ^= x0;
  x0 += k2; x1 += k0 + 5u;
  o0 = x0; o1 = x1;
}

// 5 threefry2x32 instances advanced in LOCKSTEP (forces 5-way ILP: each
// round presents 5 independent add->rotl->xor chains to the scheduler).
#define TF5_R(r)                                            \
  _Pragma("unroll") for (int i = 0; i < 5; ++i) {           \
    x0[i] += x1[i]; x1[i] = rotl32(x1[i], r) ^ x0[i];       \
  }
#define TF5_INJ(a, b)                                       \
  _Pragma("unroll") for (int i = 0; i < 5; ++i) {           \
    x0[i] += (a); x1[i] += (b);                             \
  }
__device__ __forceinline__ void threefry5(uint32_t k0, uint32_t k1,
    const uint32_t xa[5], const uint32_t xb[5], uint32_t oa[5], uint32_t ob[5]) {
  uint32_t k2 = k0 ^ k1 ^ 0x1BD11BDAu;
  uint32_t x0[5], x1[5];
  #pragma unroll
  for (int i = 0; i < 5; ++i) { x0[i] = xa[i] + k0; x1[i] = xb[i] + k1; }
  TF5_R(13) TF5_R(15) TF5_R(26) TF5_R(6)  TF5_INJ(k1, k2 + 1u)
  TF5_R(17) TF5_R(29) TF5_R(16) TF5_R(24) TF5_INJ(k2, k0 + 2u)
  TF5_R(13) TF5_R(15) TF5_R(26) TF5_R(6)  TF5_INJ(k0, k1 + 3u)
  TF5_R(17) TF5_R(29) TF5_R(16) TF5_R(24) TF5_INJ(k1, k2 + 4u)
  TF5_R(13) TF5_R(15) TF5_R(26) TF5_R(6)  TF5_INJ(k2, k0 + 5u)
  #pragma unroll
  for (int i = 0; i < 5; ++i) { oa[i] = x0[i]; ob[i] = x1[i]; }
}

// fast gumbel via v_log_f32: -ln(-ln u) = -ln2 * log2( ln2 * (-log2 u) )
#define LN2F 0.6931471805599453f
__device__ __forceinline__ float gumbel_from_bits(uint32_t bits) {
  float u = __uint_as_float((bits >> 9) | 0x3f800000u) - 1.0f;
  u = fmaxf(u, 1.17549435e-38f);
  float t = __log2f(u);
  float inner = LN2F * (-t);
  return -LN2F * __log2f(inner);
}

// ---------------------------------------------------------------------------
// weight prep: invwn[384] (1/(||w||+eps)) + bf16 weight conversion.
// W2 transposed to [co][tap][ci]. grid 274 x 256.
// ---------------------------------------------------------------------------
__global__ void wprep_k(const float* __restrict__ w1, const float* __restrict__ w2,
                        const float* __restrict__ w3, float* __restrict__ invwn,
                        unsigned short* __restrict__ W1b, unsigned short* __restrict__ W2tb,
                        unsigned short* __restrict__ W3b) {
  int i = blockIdx.x * 256 + threadIdx.x;
  if (i < 16384) {
    W1b[i] = f2bf(w1[i]);
  } else if (i < 53248) {
    int o = i - 16384;
    int co = o / 576, r = o % 576, tap = r >> 6, ci = r & 63;
    W2tb[o] = f2bf(w2[co * 576 + ci * 9 + tap]);
  } else if (i < 69632) {
    int o = i - 53248;
    W3b[o] = f2bf(w3[o]);
  } else {
    int t = i - 69632;
    if (t < 64) {
      float s = 0.f;
      for (int k = 0; k < 256; k++) { float v = w1[t * 256 + k]; s = fmaf(v, v, s); }
      invwn[t] = 1.0f / (sqrtf(s) + 1e-6f);
    } else if (t < 128) {
      int c = t - 64; float s = 0.f;
      for (int k = 0; k < 576; k++) { float v = w2[c * 576 + k]; s = fmaf(v, v, s); }
      invwn[t] = 1.0f / (sqrtf(s) + 1e-6f);
    } else if (t < 384) {
      int c = t - 128; float s = 0.f;
      for (int k = 0; k < 64; k++) { float v = w3[c * 64 + k]; s = fmaf(v, v, s); }
      invwn[t] = 1.0f / (sqrtf(s) + 1e-6f);
    }
  }
}

// ---------------------------------------------------------------------------
// BN finalize from per-block partials, channel-major [co][nblk].
// grid = C blocks, 256 threads: coalesced row sum + wave/LDS reduce.
// ---------------------------------------------------------------------------
__global__ __launch_bounds__(256) void bn_fin(const float* __restrict__ Sp,
    const float* __restrict__ Qp, const float* __restrict__ g,
    const float* __restrict__ b, float* __restrict__ sc, float* __restrict__ sh,
    int nblk) {
  const int c = blockIdx.x, tid = threadIdx.x;
  const float* rs = Sp + (size_t)c * nblk;
  const float* rq = Qp + (size_t)c * nblk;
  float s = 0.f, q = 0.f;
  for (int i = tid; i < nblk; i += 256) { s += rs[i]; q += rq[i]; }
  #pragma unroll
  for (int o = 32; o; o >>= 1) { s += __shfl_xor(s, o); q += __shfl_xor(q, o); }
  __shared__ float S[4], Q[4];
  int lane = tid & 63, wave = tid >> 6;
  if (lane == 0) { S[wave] = s; Q[wave] = q; }
  __syncthreads();
  if (tid == 0) {
    float st = S[0] + S[1] + S[2] + S[3];
    float qt = Q[0] + Q[1] + Q[2] + Q[3];
    float mean = st * (1.0f / (float)NPIX);
    float var = qt * (1.0f / (float)NPIX) - mean * mean;  // biased, jnp.var
    float sv = g[c] / sqrtf(var + 1e-5f);
    sc[c] = sv; sh[c] = b[c] - mean * sv;
  }
}

// ---------------------------------------------------------------------------
// conv1: 1x1 256->64 MFMA. Block = 64px x 64co, grid (49,16).
// Outputs: y1 bf16 pixel-major [b][hw][64], CS1 bf16 channel-major,
// BN partials [co][784] (non-atomic).
// ---------------------------------------------------------------------------
__global__ __launch_bounds__(256) void conv1_mfma(
    const float* __restrict__ X, const unsigned short* __restrict__ Wb,
    const float* __restrict__ invwn, unsigned short* __restrict__ Y1,
    unsigned short* __restrict__ CS, float* __restrict__ Sp, float* __restrict__ Qp) {
#define ST1 264
#define NB1 784
  __shared__ __align__(16) unsigned short bq[64 * ST1];
  __shared__ float sqp[4][64];
  __shared__ float ixn[64];
  const int p0 = blockIdx.x * 64, b = blockIdx.y;
  const int bid = b * 49 + blockIdx.x;
  const int tid = threadIdx.x;
  const int lane = tid & 63, wave = tid >> 6;
  const int m = lane & 15, quad = lane >> 4;
  const int co0 = wave * 16;
  const float* Xb = X + (size_t)b * 256 * HW + p0;

  bf16x8 afr[8];
  const unsigned short* wrow = Wb + (co0 + m) * 256 + quad * 8;
  #pragma unroll
  for (int k = 0; k < 8; ++k) afr[k] = *(const bf16x8*)(wrow + k * 32);

  {
    const int px = tid & 63, rg = tid >> 6;
    float sq = 0.f;
    #pragma unroll
    for (int it = 0; it < 16; ++it) {
      int ci = rg * 64 + it * 4;
      float v0 = Xb[(size_t)(ci + 0) * HW + px];
      float v1 = Xb[(size_t)(ci + 1) * HW + px];
      float v2 = Xb[(size_t)(ci + 2) * HW + px];
      float v3 = Xb[(size_t)(ci + 3) * HW + px];
      sq += v0 * v0 + v1 * v1 + v2 * v2 + v3 * v3;
      *(uint2*)&bq[px * ST1 + ci] = make_uint2(pk2(v0, v1), pk2(v2, v3));
    }
    sqp[rg][px] = sq;
  }
  __syncthreads();
  if (tid < 64)
    ixn[tid] = 1.0f / (sqrtf(sqp[0][tid] + sqp[1][tid] + sqp[2][tid] + sqp[3][tid]) + 1e-6f);
  __syncthreads();

  f32x4 acc[4];
  #pragma unroll
  for (int nt = 0; nt < 4; ++nt) acc[nt] = (f32x4)0.f;
  #pragma unroll
  for (int nt = 0; nt < 4; ++nt) {
    const unsigned short* brow = &bq[(nt * 16 + m) * ST1 + quad * 8];
    #pragma unroll
    for (int k = 0; k < 8; ++k) {
      bf16x8 bfrag = *(const bf16x8*)(brow + k * 32);
      acc[nt] = MFMA16(afr[k], bfrag, acc[nt]);
    }
  }

  float s[4] = {0, 0, 0, 0}, q[4] = {0, 0, 0, 0};
  #pragma unroll
  for (int nt = 0; nt < 4; ++nt) {
    int px = nt * 16 + m;
    size_t bp = (size_t)b * HW + p0 + px;
    float ix = ixn[px];
    *(uint2*)&Y1[bp * 64 + co0 + quad * 4] =
        make_uint2(pk2(acc[nt][0], acc[nt][1]), pk2(acc[nt][2], acc[nt][3]));
    #pragma unroll
    for (int r = 0; r < 4; ++r) {
      int co = co0 + quad * 4 + r;
      float v = acc[nt][r];
      CS[((size_t)b * 64 + co) * HW + p0 + px] = f2bf(v * invwn[co] * ix);
      s[r] += v; q[r] = fmaf(v, v, q[r]);
    }
  }
  #pragma unroll
  for (int r = 0; r < 4; ++r) {
    float ss = s[r], qq = q[r];
    #pragma unroll
    for (int o = 8; o; o >>= 1) { ss += __shfl_xor(ss, o); qq += __shfl_xor(qq, o); }
    if (m == 0) {
      int co = co0 + quad * 4 + r;
      Sp[(size_t)co * NB1 + bid] = ss; Qp[(size_t)co * NB1 + bid] = qq;
    }
  }
#undef NB1
#undef ST1
}

// ---------------------------------------------------------------------------
// per-pixel sum over 64 ci of relu(bn1(y1))^2, y1 bf16 pixel-major. grid 196.
// ---------------------------------------------------------------------------
__global__ __launch_bounds__(256) void chansum_px(const unsigned short* __restrict__ Y1,
    const float* __restrict__ sc, const float* __restrict__ sh,
    float* __restrict__ part) {
  int g = blockIdx.x * 256 + threadIdx.x;
  const unsigned short* row = Y1 + (size_t)g * 64;
  float s = 0.f;
  #pragma unroll
  for (int j = 0; j < 8; ++j) {
    uint4 d = *(const uint4*)(row + j * 8);
    unsigned dd[4] = {d.x, d.y, d.z, d.w};
    #pragma unroll
    for (int e = 0; e < 4; ++e) {
      int c = j * 8 + e * 2;
      float v0 = fmaxf(0.f, fmaf(bf2f((unsigned short)(dd[e] & 0xffff)), sc[c], sh[c]));
      float v1 = fmaxf(0.f, fmaf(bf2f((unsigned short)(dd[e] >> 16)), sc[c + 1], sh[c + 1]));
      s = fmaf(v0, v0, s); s = fmaf(v1, v1, s);
    }
  }
  part[g] = s;
}

// 3x3 box-sum (zero pad) of part -> 1/(sqrt(.)+1e-6). grid 196
__global__ __launch_bounds__(256) void box3inv(const float* __restrict__ part,
                                               float* __restrict__ out) {
  int g = blockIdx.x * 256 + threadIdx.x;
  int b = g / HW, p = g - b * HW;
  int y = p / 56, x = p % 56;
  float tot = 0.f;
  for (int dy = -1; dy <= 1; dy++) {
    int yy = y + dy; if (yy < 0 || yy >= 56) continue;
    for (int dx = -1; dx <= 1; dx++) {
      int xx = x + dx; if (xx < 0 || xx >= 56) continue;
      tot += part[b * HW + yy * 56 + xx];
    }
  }
  out[g] = 1.0f / (sqrtf(tot) + 1e-6f);
}

// ---------------------------------------------------------------------------
// conv2: 3x3 64->64 pad1, implicit-GEMM MFMA. grid (56,16). CS bf16.
// BN partials [co][896] non-atomic.
// ---------------------------------------------------------------------------
__global__ __launch_bounds__(256) void conv2_mfma(
    const unsigned short* __restrict__ Y1, const unsigned short* __restrict__ W2tb,
    const float* __restrict__ invwn, const float* __restrict__ ixn2,
    const float* __restrict__ sc1, const float* __restrict__ sh1,
    unsigned short* __restrict__ Y2, unsigned short* __restrict__ CS,
    float* __restrict__ Sp, float* __restrict__ Qp) {
#define STW 72
#define NB2 896
  __shared__ __align__(16) unsigned short ts[3 * 66 * STW];
  __shared__ float scl[64], shl[64];
  const int h = blockIdx.x, b = blockIdx.y;
  const int bid = b * 56 + h;
  const int tid = threadIdx.x;
  const int lane = tid & 63, wave = tid >> 6;
  const int m = lane & 15, quad = lane >> 4;
  const int co0 = wave * 16;
  if (tid < 64) { scl[tid] = sc1[tid]; shl[tid] = sh1[tid]; }

  bf16x8 afr[18];
  #pragma unroll
  for (int ks = 0; ks < 18; ++ks)
    afr[ks] = *(const bf16x8*)(W2tb + (co0 + m) * 576 + ks * 32 + quad * 8);
  __syncthreads();

  for (int l = tid; l < 6336; l += 256) {  // 3 rows x 66 cols x 32 ci-pairs
    int cp = l & 31, cc = (l >> 5) % 66, dy = l / 2112;
    int yy = h - 1 + dy, xx = cc - 1;
    unsigned pkv = 0u;
    if (yy >= 0 && yy < 56 && xx >= 0 && xx < 56) {
      unsigned d = *(const unsigned*)&Y1[((size_t)b * HW + yy * 56 + xx) * 64 + cp * 2];
      float v0 = bf2f((unsigned short)(d & 0xffff));
      float v1 = bf2f((unsigned short)(d >> 16));
      v0 = fmaxf(0.f, fmaf(v0, scl[cp * 2], shl[cp * 2]));
      v1 = fmaxf(0.f, fmaf(v1, scl[cp * 2 + 1], shl[cp * 2 + 1]));
      pkv = pk2(v0, v1);
    }
    *(unsigned*)&ts[(dy * 66 + cc) * STW + cp * 2] = pkv;
  }
  __syncthreads();

  f32x4 acc[4];
  #pragma unroll
  for (int nt = 0; nt < 4; ++nt) acc[nt] = (f32x4)0.f;
  #pragma unroll
  for (int nt = 0; nt < 4; ++nt) {
    #pragma unroll
    for (int ks = 0; ks < 18; ++ks) {
      int tap = ks >> 1, half = ks & 1;
      int dy = tap / 3, dx = tap % 3;
      bf16x8 bfrag = *(const bf16x8*)&ts[(dy * 66 + nt * 16 + m + dx) * STW + half * 32 + quad * 8];
      acc[nt] = MFMA16(afr[ks], bfrag, acc[nt]);
    }
  }

  float s[4] = {0, 0, 0, 0}, q[4] = {0, 0, 0, 0};
  #pragma unroll
  for (int nt = 0; nt < 4; ++nt) {
    int px = nt * 16 + m;
    bool valid = px < 56;
    int pix = h * 56 + px;
    if (valid) {
      float ix = ixn2[b * HW + pix];
      size_t bp = (size_t)b * HW + pix;
      *(uint2*)&Y2[bp * 64 + co0 + quad * 4] =
          make_uint2(pk2(acc[nt][0], acc[nt][1]), pk2(acc[nt][2], acc[nt][3]));
      #pragma unroll
      for (int r = 0; r < 4; ++r) {
        int co = co0 + quad * 4 + r;
        CS[((size_t)b * 64 + co) * HW + pix] = f2bf(acc[nt][r] * invwn[co] * ix);
      }
    }
    #pragma unroll
    for (int r = 0; r < 4; ++r) {
      float v = valid ? acc[nt][r] : 0.f;
      s[r] += v; q[r] = fmaf(v, v, q[r]);
    }
  }
  #pragma unroll
  for (int r = 0; r < 4; ++r) {
    float ss = s[r], qq = q[r];
    #pragma unroll
    for (int o = 8; o; o >>= 1) { ss += __shfl_xor(ss, o); qq += __shfl_xor(qq, o); }
    if (m == 0) {
      int co = co0 + quad * 4 + r;
      Sp[(size_t)co * NB2 + bid] = ss; Qp[(size_t)co * NB2 + bid] = qq;
    }
  }
#undef NB2
#undef STW
}

// ---------------------------------------------------------------------------
// conv3: 1x1 64->256 MFMA. grid (49,16). Outputs y3 bf16 + cos3 bf16
// channel-major, BN partials [co][784] non-atomic.
// ---------------------------------------------------------------------------
__global__ __launch_bounds__(256) void conv3_mfma(
    const unsigned short* __restrict__ Y2, const unsigned short* __restrict__ W3b,
    const float* __restrict__ invwn,
    const float* __restrict__ sc2, const float* __restrict__ sh2,
    unsigned short* __restrict__ Y3, unsigned short* __restrict__ CS,
    float* __restrict__ Sp, float* __restrict__ Qp) {
#define ST3 72
#define NB3 784
  __shared__ __align__(16) unsigned short bq[64 * ST3];
  __shared__ float scl[64], shl[64], sqp[4][64], ixn[64];
  const int p0 = blockIdx.x * 64, b = blockIdx.y;
  const int bid = b * 49 + blockIdx.x;
  const int tid = threadIdx.x;
  const int lane = tid & 63, wave = tid >> 6;
  const int m = lane & 15, quad = lane >> 4;
  const int co0 = wave * 64;
  if (tid < 64) { scl[tid] = sc2[tid]; shl[tid] = sh2[tid]; }

  bf16x8 afr[4][2];
  #pragma unroll
  for (int mt = 0; mt < 4; ++mt)
    #pragma unroll
    for (int k = 0; k < 2; ++k)
      afr[mt][k] = *(const bf16x8*)(W3b + (co0 + mt * 16 + m) * 64 + k * 32 + quad * 8);
  __syncthreads();

  {
    const int cp = tid & 31, pxg = tid >> 5;
    #pragma unroll
    for (int it = 0; it < 8; ++it) {
      int px = pxg * 8 + it;
      unsigned d = *(const unsigned*)&Y2[((size_t)b * HW + p0 + px) * 64 + cp * 2];
      float v0 = bf2f((unsigned short)(d & 0xffff));
      float v1 = bf2f((unsigned short)(d >> 16));
      v0 = fmaxf(0.f, fmaf(v0, scl[cp * 2], shl[cp * 2]));
      v1 = fmaxf(0.f, fmaf(v1, scl[cp * 2 + 1], shl[cp * 2 + 1]));
      *(unsigned*)&bq[px * ST3 + cp * 2] = pk2(v0, v1);
    }
  }
  __syncthreads();
  {
    const int px = tid & 63, hh = tid >> 6;
    const unsigned short* row = &bq[px * ST3 + hh * 16];
    float sq = 0.f;
    #pragma unroll
    for (int e = 0; e < 16; ++e) { float v = bf2f(row[e]); sq = fmaf(v, v, sq); }
    sqp[hh][px] = sq;
  }
  __syncthreads();
  if (tid < 64)
    ixn[tid] = 1.0f / (sqrtf(sqp[0][tid] + sqp[1][tid] + sqp[2][tid] + sqp[3][tid]) + 1e-6f);
  __syncthreads();

  f32x4 acc[4][4];
  #pragma unroll
  for (int mt = 0; mt < 4; ++mt)
    #pragma unroll
    for (int nt = 0; nt < 4; ++nt) acc[mt][nt] = (f32x4)0.f;
  #pragma unroll
  for (int nt = 0; nt < 4; ++nt) {
    const unsigned short* brow = &bq[(nt * 16 + m) * ST3 + quad * 8];
    bf16x8 b0 = *(const bf16x8*)(brow);
    bf16x8 b1 = *(const bf16x8*)(brow + 32);
    #pragma unroll
    for (int mt = 0; mt < 4; ++mt) {
      acc[mt][nt] = MFMA16(afr[mt][0], b0, acc[mt][nt]);
      acc[mt][nt] = MFMA16(afr[mt][1], b1, acc[mt][nt]);
    }
  }

  #pragma unroll
  for (int mt = 0; mt < 4; ++mt) {
    float s[4] = {0, 0, 0, 0}, q[4] = {0, 0, 0, 0};
    #pragma unroll
    for (int nt = 0; nt < 4; ++nt) {
      int px = nt * 16 + m;
      float ix = ixn[px];
      #pragma unroll
      for (int r = 0; r < 4; ++r) {
        int co = co0 + mt * 16 + quad * 4 + r;
        float v = acc[mt][nt][r];
        size_t off = ((size_t)b * 256 + co) * HW + p0 + px;
        Y3[off] = f2bf(v);
        CS[off] = f2bf(v * invwn[co] * ix);
        s[r] += v; q[r] = fmaf(v, v, q[r]);
      }
    }
    #pragma unroll
    for (int r = 0; r < 4; ++r) {
      float ss = s[r], qq = q[r];
      #pragma unroll
      for (int o = 8; o; o >>= 1) { ss += __shfl_xor(ss, o); qq += __shfl_xor(qq, o); }
      if (m == 0) {
        int co = co0 + mt * 16 + quad * 4 + r;
        Sp[(size_t)co * NB3 + bid] = ss; Qp[(size_t)co * NB3 + bid] = qq;
      }
    }
  }
#undef NB3
#undef ST3
}

// ---------------------------------------------------------------------------
// sample5: one block per cell-pair (u, u+BC/2), ALL 5 samples per cell.
// Counter identities (n = 5*BC*HW, halfn = n/2 = 2.5*sC, sC = BC*HW,
// eU = u*HW+p, eV = eU + sC/2):
//   u: t0,t1,t2 = o0(eU + t*sC);  t3 = o1(eV), t4 = o1(eV + sC)
//   v: t0,t1    = o0(eV + t*sC);  t2 = o1(eU), t3 = o1(eU+sC), t4 = o1(eU+2sC)
// launch_bounds(256,4): VGPR cap 128 so the 5 lockstep threefry chains +
// 10 gumbel log chains stay live and interleave (R6 @32 VGPR was stall-bound).
// ---------------------------------------------------------------------------
__global__ __launch_bounds__(256, 4) void sample5_k(const unsigned short* __restrict__ CS,
    float* __restrict__ acc, uint32_t key0, uint32_t key1, int BC, float scale) {
  const int u = blockIdx.x;
  const int v = u + (BC >> 1);
  const uint32_t sC = (uint32_t)BC * (uint32_t)HW;     // counter stride per sample
  const uint32_t halfn = sC * 2u + (sC >> 1);          // 5*BC*HW/2
  const unsigned short* rowU = CS + (size_t)u * HW;
  const unsigned short* rowV = CS + (size_t)v * HW;
  const int tid = threadIdx.x;
  const int lane = tid & 63, wave = tid >> 6;

  // slots 0..4: cell u samples; 5..9: cell v samples
  float bst[10]; int idx[10];
  #pragma unroll
  for (int k = 0; k < 10; ++k) { bst[k] = -INFINITY; idx[k] = 0; }

  const uint32_t baseU0 = (uint32_t)u * (uint32_t)HW;
  const uint32_t baseV0 = (uint32_t)v * (uint32_t)HW;
  for (int p = tid; p < HW; p += 256) {
    float lu = 2.0f * bf2f(rowU[p]);
    float lv = 2.0f * bf2f(rowV[p]);
    uint32_t eU = baseU0 + (uint32_t)p;
    uint32_t eV = baseV0 + (uint32_t)p;
    uint32_t xa[5] = {eU, eU + sC, eU + 2 * sC, eV, eV + sC};
    uint32_t xb[5] = {eU + halfn, eU + sC + halfn, eU + 2 * sC + halfn,
                      eV + halfn, eV + sC + halfn};
    uint32_t oa[5], ob[5];
    threefry5(key0, key1, xa, xb, oa, ob);
    // 10 gumbels in unrolled arrays -> interleaved log chains
    float gu[5], gv[5];
    gu[0] = gumbel_from_bits(oa[0]);   // u s0
    gu[1] = gumbel_from_bits(oa[1]);   // u s1
    gu[2] = gumbel_from_bits(oa[2]);   // u s2
    gu[3] = gumbel_from_bits(ob[3]);   // u s3
    gu[4] = gumbel_from_bits(ob[4]);   // u s4
    gv[0] = gumbel_from_bits(oa[3]);   // v s0
    gv[1] = gumbel_from_bits(oa[4]);   // v s1
    gv[2] = gumbel_from_bits(ob[0]);   // v s2
    gv[3] = gumbel_from_bits(ob[1]);   // v s3
    gv[4] = gumbel_from_bits(ob[2]);   // v s4
    #pragma unroll
    for (int k = 0; k < 5; ++k) {
      float su = lu + gu[k];
      float sv = lv + gv[k];
      if (su > bst[k])     { bst[k] = su;     idx[k] = p; }
      if (sv > bst[5 + k]) { bst[5 + k] = sv; idx[5 + k] = p; }
    }
  }

  // wave butterfly argmax (ties -> smaller index), then cross-wave in LDS
  __shared__ float rv[10][4];
  __shared__ int   ri[10][4];
  __shared__ int   widx[10];
  __shared__ float wsum[10];
  #pragma unroll
  for (int k = 0; k < 10; ++k) {
    float val = bst[k]; int ix = idx[k];
    #pragma unroll
    for (int o = 32; o; o >>= 1) {
      float ov = __shfl_xor(val, o); int oi = __shfl_xor(ix, o);
      if (ov > val || (ov == val && oi < ix)) { val = ov; ix = oi; }
    }
    if (lane == 0) { rv[k][wave] = val; ri[k][wave] = ix; }
  }
  if (tid < 10) wsum[tid] = 0.f;
  __syncthreads();
  if (tid < 10) {
    float val = rv[tid][0]; int ix = ri[tid][0];
    #pragma unroll
    for (int wv = 1; wv < 4; ++wv) {
      float ov = rv[tid][wv]; int oi = ri[tid][wv];
      if (ov > val || (ov == val && oi < ix)) { val = ov; ix = oi; }
    }
    widx[tid] = ix;
  }
  __syncthreads();

  // 11x11 zero-padded window sums around the 10 winners
  int c2 = tid >> 7, j = tid & 127;
  if (j < 121) {
    int dy = j / 11 - 5, dxx = j % 11 - 5;
    #pragma unroll
    for (int k = 0; k < 5; ++k) {
      int win = k * 2 + c2;
      int bidx = widx[win];
      int py = bidx / 56, px = bidx % 56;
      int yy = py + dy, xx = px + dxx;
      if (yy >= 0 && yy < 56 && xx >= 0 && xx < 56) {
        const unsigned short* row = (win < 5) ? rowU : rowV;
        atomicAdd(&wsum[win], bf2f(row[yy * 56 + xx]));
      }
    }
  }
  __syncthreads();
  if (tid == 0) {
    float t = 0.f;
    #pragma unroll
    for (int k = 0; k < 10; ++k) t += wsum[k];
    atomicAdd(acc, t * scale);
  }
}

// ---------------------------------------------------------------------------
// out = relu(bn3(y3) + x), y3 bf16; emits acc scalar at out[12845056]
// ---------------------------------------------------------------------------
__global__ __launch_bounds__(256) void final_k(const unsigned short* __restrict__ Y3,
    const float* __restrict__ X, const float* __restrict__ sc,
    const float* __restrict__ sh, const float* __restrict__ acc,
    float* __restrict__ out) {
  size_t i4 = (size_t)blockIdx.x * 256 + threadIdx.x;
  if (i4 == 0) out[12845056] = acc[0];
  size_t i = i4 * 4;
  int c = (int)((i / HW) % 256);
  float a = sc[c], d = sh[c];
  uint2 yd = *(const uint2*)&Y3[i];
  float4 xv = *(const float4*)&X[i];
  float4 r;
  r.x = fmaxf(0.f, fmaf(bf2f((unsigned short)(yd.x & 0xffff)), a, d) + xv.x);
  r.y = fmaxf(0.f, fmaf(bf2f((unsigned short)(yd.x >> 16)),    a, d) + xv.y);
  r.z = fmaxf(0.f, fmaf(bf2f((unsigned short)(yd.y & 0xffff)), a, d) + xv.z);
  r.w = fmaxf(0.f, fmaf(bf2f((unsigned short)(yd.y >> 16)),    a, d) + xv.w);
  *(float4*)&out[i] = r;
}

// ---------------------------------------------------------------------------
extern "C" void kernel_launch(void* const* d_in, const int* in_sizes, int n_in,
                              void* d_out, int out_size, void* d_ws, size_t ws_size,
                              hipStream_t stream) {
  (void)in_sizes; (void)n_in; (void)out_size; (void)ws_size;
  const float* x  = (const float*)d_in[0];
  const float* w1 = (const float*)d_in[1];
  const float* w2 = (const float*)d_in[2];
  const float* w3 = (const float*)d_in[3];
  const float* g1 = (const float*)d_in[4];
  const float* b1 = (const float*)d_in[5];
  const float* g2 = (const float*)d_in[6];
  const float* b2 = (const float*)d_in[7];
  const float* g3 = (const float*)d_in[8];
  const float* b3 = (const float*)d_in[9];
  float* out = (float*)d_out;
  float* ws = (float*)d_ws;

  // workspace layout (float units; bf16 buffers use elems/2 float units)
  size_t o = 0;
  unsigned short* y3b  = (unsigned short*)(ws + o); o += 6422528;  // 12845056 bf16
  unsigned short* cos3 = (unsigned short*)(ws + o); o += 6422528;  // 12845056 bf16
  unsigned short* CSb  = (unsigned short*)(ws + o); o += 1605632;  // 3211264 bf16
  unsigned short* y1b  = (unsigned short*)(ws + o); o += 1605632;  // 3211264 bf16
  unsigned short* y2b  = (unsigned short*)(ws + o); o += 1605632;  // 3211264 bf16
  unsigned short* W1b  = (unsigned short*)(ws + o); o += 8192;     // 16384 bf16
  unsigned short* W2tb = (unsigned short*)(ws + o); o += 18432;    // 36864 bf16
  unsigned short* W3b  = (unsigned short*)(ws + o); o += 8192;     // 16384 bf16
  float* part = ws + o; o += NPIX;
  float* ixn2 = ws + o; o += NPIX;
  float* invwn = ws + o; o += 384;
  // BN per-block partials, channel-major [co][nblk] (every slot written)
  float* Sp1 = ws + o; o += 64 * 784;   float* Qp1 = ws + o; o += 64 * 784;
  float* Sp2 = ws + o; o += 64 * 896;   float* Qp2 = ws + o; o += 64 * 896;
  float* Sp3 = ws + o; o += 256 * 784;  float* Qp3 = ws + o; o += 256 * 784;
  float* acc = ws + o; o += 1;
  float* sc1 = ws + o; o += 64;  float* sh1 = ws + o; o += 64;
  float* sc2 = ws + o; o += 64;  float* sh2 = ws + o; o += 64;
  float* sc3 = ws + o; o += 256; float* sh3 = ws + o; o += 256;

  hipMemsetAsync(acc, 0, sizeof(float), stream);

  // JAX: k0,k1,k2 = split(key(42), 3); (Ai,Bi) = threefry2x32((0,42),(i,i+3))
  uint32_t A0, B0, A1, B1, A2, B2;
  threefry2x32(0u, 42u, 0u, 3u, A0, B0);
  threefry2x32(0u, 42u, 1u, 4u, A1, B1);
  threefry2x32(0u, 42u, 2u, 5u, A2, B2);

  const float scale64  = 1.0f / (121.0f * 5.0f * 1024.0f);
  const float scale256 = 1.0f / (121.0f * 5.0f * 4096.0f);

  wprep_k<<<274, 256, 0, stream>>>(w1, w2, w3, invwn, W1b, W2tb, W3b);

  // stage 1: 1x1 conv 256->64 (MFMA) + BN1 partials
  conv1_mfma<<<dim3(49, 16), 256, 0, stream>>>(x, W1b, invwn, y1b, CSb, Sp1, Qp1);
  bn_fin<<<64, 256, 0, stream>>>(Sp1, Qp1, g1, b1, sc1, sh1, 784);
  sample5_k<<<512, 256, 0, stream>>>(CSb, acc, A0, A1, 1024, scale64);

  // stage 2: 3x3 conv 64->64 pad 1 (MFMA), t1 = relu(bn1(y1)) inline
  chansum_px<<<196, 256, 0, stream>>>(y1b, sc1, sh1, part);
  box3inv<<<196, 256, 0, stream>>>(part, ixn2);
  conv2_mfma<<<dim3(56, 16), 256, 0, stream>>>(
      y1b, W2tb, invwn + 64, ixn2, sc1, sh1, y2b, CSb, Sp2, Qp2);
  bn_fin<<<64, 256, 0, stream>>>(Sp2, Qp2, g2, b2, sc2, sh2, 896);
  sample5_k<<<512, 256, 0, stream>>>(CSb, acc, A2, B0, 1024, scale64);

  // stage 3: 1x1 conv 64->256 (MFMA), t2 = relu(bn2(y2)) inline
  conv3_mfma<<<dim3(49, 16), 256, 0, stream>>>(
      y2b, W3b, invwn + 128, sc2, sh2, y3b, cos3, Sp3, Qp3);
  bn_fin<<<256, 256, 0, stream>>>(Sp3, Qp3, g3, b3, sc3, sh3, 784);
  sample5_k<<<2048, 256, 0, stream>>>(cos3, acc, B1, B2, 4096, scale256);
  final_k<<<12544, 256, 0, stream>>>(y3b, x, sc3, sh3, acc, out);
}

// Round 8
// 382.340 us; speedup vs baseline: 1.0479x; 1.0479x over previous
//
#include <hip/hip_runtime.h>
#include <stdint.h>
#include <math.h>

// Problem constants: B=16, H=W=56, HW=3136, pipeline 256 -> 64 -> 64 -> 256
#define HW 3136
#define NPIX 50176  // 16*3136

// ---------------------------------------------------------------------------
// MFMA types & helpers (gfx950 v_mfma_f32_16x16x32_bf16)
// ---------------------------------------------------------------------------
typedef __attribute__((ext_vector_type(8))) short bf16x8;
typedef __attribute__((ext_vector_type(4))) float f32x4;
#define MFMA16(a, b, c) __builtin_amdgcn_mfma_f32_16x16x32_bf16(a, b, c, 0, 0, 0)

__device__ __forceinline__ unsigned short f2bf(float f) {  // RNE f32->bf16
  unsigned u = __float_as_uint(f);
  u = (u + 0x7fffu + ((u >> 16) & 1u)) >> 16;
  return (unsigned short)u;
}
__device__ __forceinline__ unsigned pk2(float a, float b) {
  return (unsigned)f2bf(a) | ((unsigned)f2bf(b) << 16);
}
__device__ __forceinline__ float bf2f(unsigned short h) {
  return __uint_as_float(((unsigned)h) << 16);
}

// ---------------------------------------------------------------------------
// threefry2x32 (Random123 / JAX-exact). ROTL = single v_alignbit via builtin.
// ---------------------------------------------------------------------------
#define ROTL32(v, r) __builtin_rotateleft32((uint32_t)(v), (r))

__host__ __device__ inline void threefry2x32(uint32_t k0, uint32_t k1,
                                             uint32_t x0, uint32_t x1,
                                             uint32_t& o0, uint32_t& o1) {
  uint32_t k2 = k0 ^ k1 ^ 0x1BD11BDAu;
  x0 += k0; x1 += k1;
  x0 += x1; x1 = ROTL32(x1, 13); x1 ^= x0;
  x0 += x1; x1 = ROTL32(x1, 15); x1 ^= x0;
  x0 += x1; x1 = ROTL32(x1, 26); x1 ^= x0;
  x0 += x1; x1 = ROTL32(x1, 6);  x1 ^= x0;
  x0 += k1; x1 += k2 + 1u;
  x0 += x1; x1 = ROTL32(x1, 17); x1 ^= x0;
  x0 += x1; x1 = ROTL32(x1, 29); x1 ^= x0;
  x0 += x1; x1 = ROTL32(x1, 16); x1 ^= x0;
  x0 += x1; x1 = ROTL32(x1, 24); x1 ^= x0;
  x0 += k2; x1 += k0 + 2u;
  x0 += x1; x1 = ROTL32(x1, 13); x1 ^= x0;
  x0 += x1; x1 = ROTL32(x1, 15); x1 ^= x0;
  x0 += x1; x1 = ROTL32(x1, 26); x1 ^= x0;
  x0 += x1; x1 = ROTL32(x1, 6);  x1 ^= x0;
  x0 += k0; x1 += k1 + 3u;
  x0 += x1; x1 = ROTL32(x1, 17); x1 ^= x0;
  x0 += x1; x1 = ROTL32(x1, 29); x1 ^= x0;
  x0 += x1; x1 = ROTL32(x1, 16); x1 ^= x0;
  x0 += x1; x1 = ROTL32(x1, 24); x1 ^= x0;
  x0 += k1; x1 += k2 + 4u;
  x0 += x1; x1 = ROTL32(x1, 13); x1 ^= x0;
  x0 += x1; x1 = ROTL32(x1, 15); x1 ^= x0;
  x0 += x1; x1 = ROTL32(x1, 26); x1 ^= x0;
  x0 += x1; x1 = ROTL32(x1, 6);  x1 ^= x0;
  x0 += k2; x1 += k0 + 5u;
  o0 = x0; o1 = x1;
}

// 5 threefry2x32 instances in lockstep (single-instr rotations).
#define TF5_R(r)                                            \
  _Pragma("unroll") for (int i = 0; i < 5; ++i) {           \
    x0[i] += x1[i]; x1[i] = ROTL32(x1[i], r) ^ x0[i];       \
  }
#define TF5_INJ(a, b)                                       \
  _Pragma("unroll") for (int i = 0; i < 5; ++i) {           \
    x0[i] += (a); x1[i] += (b);                             \
  }
__device__ __forceinline__ void threefry5(uint32_t k0, uint32_t k1,
    const uint32_t xa[5], const uint32_t xb[5], uint32_t oa[5], uint32_t ob[5]) {
  uint32_t k2 = k0 ^ k1 ^ 0x1BD11BDAu;
  uint32_t x0[5], x1[5];
  #pragma unroll
  for (int i = 0; i < 5; ++i) { x0[i] = xa[i] + k0; x1[i] = xb[i] + k1; }
  TF5_R(13) TF5_R(15) TF5_R(26) TF5_R(6)  TF5_INJ(k1, k2 + 1u)
  TF5_R(17) TF5_R(29) TF5_R(16) TF5_R(24) TF5_INJ(k2, k0 + 2u)
  TF5_R(13) TF5_R(15) TF5_R(26) TF5_R(6)  TF5_INJ(k0, k1 + 3u)
  TF5_R(17) TF5_R(29) TF5_R(16) TF5_R(24) TF5_INJ(k1, k2 + 4u)
  TF5_R(13) TF5_R(15) TF5_R(26) TF5_R(6)  TF5_INJ(k2, k0 + 5u)
  #pragma unroll
  for (int i = 0; i < 5; ++i) { oa[i] = x0[i]; ob[i] = x1[i]; }
}

// exp-race form: argmax(l + gumbel) == argmin( (-ln u) * exp(-l) ).
// e = (-ln2)*log2(u) >= 0; weight exp(-l) = exp2(c * -2*log2(e)) per cell.
#define NLN2F -0.6931471805599453f
#define NEG2LOG2E -2.8853900817779268f
__device__ __forceinline__ float exp_draw(uint32_t bits) {
  float u = __uint_as_float((bits >> 9) | 0x3f800000u) - 1.0f;
  u = fmaxf(u, 1.17549435e-38f);
  return NLN2F * __log2f(u);   // -ln(u) >= 0
}

// ---------------------------------------------------------------------------
// weight prep: invwn[384] (1/(||w||+eps)) + bf16 weight conversion.
// ---------------------------------------------------------------------------
__global__ void wprep_k(const float* __restrict__ w1, const float* __restrict__ w2,
                        const float* __restrict__ w3, float* __restrict__ invwn,
                        unsigned short* __restrict__ W1b, unsigned short* __restrict__ W2tb,
                        unsigned short* __restrict__ W3b) {
  int i = blockIdx.x * 256 + threadIdx.x;
  if (i < 16384) {
    W1b[i] = f2bf(w1[i]);
  } else if (i < 53248) {
    int o = i - 16384;
    int co = o / 576, r = o % 576, tap = r >> 6, ci = r & 63;
    W2tb[o] = f2bf(w2[co * 576 + ci * 9 + tap]);
  } else if (i < 69632) {
    int o = i - 53248;
    W3b[o] = f2bf(w3[o]);
  } else {
    int t = i - 69632;
    if (t < 64) {
      float s = 0.f;
      for (int k = 0; k < 256; k++) { float v = w1[t * 256 + k]; s = fmaf(v, v, s); }
      invwn[t] = 1.0f / (sqrtf(s) + 1e-6f);
    } else if (t < 128) {
      int c = t - 64; float s = 0.f;
      for (int k = 0; k < 576; k++) { float v = w2[c * 576 + k]; s = fmaf(v, v, s); }
      invwn[t] = 1.0f / (sqrtf(s) + 1e-6f);
    } else if (t < 384) {
      int c = t - 128; float s = 0.f;
      for (int k = 0; k < 64; k++) { float v = w3[c * 64 + k]; s = fmaf(v, v, s); }
      invwn[t] = 1.0f / (sqrtf(s) + 1e-6f);
    }
  }
}

// ---------------------------------------------------------------------------
// BN finalize from per-block partials, channel-major [co][nblk].
// ---------------------------------------------------------------------------
__global__ __launch_bounds__(256) void bn_fin(const float* __restrict__ Sp,
    const float* __restrict__ Qp, const float* __restrict__ g,
    const float* __restrict__ b, float* __restrict__ sc, float* __restrict__ sh,
    int nblk) {
  const int c = blockIdx.x, tid = threadIdx.x;
  const float* rs = Sp + (size_t)c * nblk;
  const float* rq = Qp + (size_t)c * nblk;
  float s = 0.f, q = 0.f;
  for (int i = tid; i < nblk; i += 256) { s += rs[i]; q += rq[i]; }
  #pragma unroll
  for (int o = 32; o; o >>= 1) { s += __shfl_xor(s, o); q += __shfl_xor(q, o); }
  __shared__ float S[4], Q[4];
  int lane = tid & 63, wave = tid >> 6;
  if (lane == 0) { S[wave] = s; Q[wave] = q; }
  __syncthreads();
  if (tid == 0) {
    float st = S[0] + S[1] + S[2] + S[3];
    float qt = Q[0] + Q[1] + Q[2] + Q[3];
    float mean = st * (1.0f / (float)NPIX);
    float var = qt * (1.0f / (float)NPIX) - mean * mean;  // biased, jnp.var
    float sv = g[c] / sqrtf(var + 1e-5f);
    sc[c] = sv; sh[c] = b[c] - mean * sv;
  }
}

// ---------------------------------------------------------------------------
// conv1: 1x1 256->64 MFMA. Block = 64px x 64co, grid (49,16).
// ---------------------------------------------------------------------------
__global__ __launch_bounds__(256) void conv1_mfma(
    const float* __restrict__ X, const unsigned short* __restrict__ Wb,
    const float* __restrict__ invwn, unsigned short* __restrict__ Y1,
    unsigned short* __restrict__ CS, float* __restrict__ Sp, float* __restrict__ Qp) {
#define ST1 264
#define NB1 784
  __shared__ __align__(16) unsigned short bq[64 * ST1];
  __shared__ float sqp[4][64];
  __shared__ float ixn[64];
  const int p0 = blockIdx.x * 64, b = blockIdx.y;
  const int bid = b * 49 + blockIdx.x;
  const int tid = threadIdx.x;
  const int lane = tid & 63, wave = tid >> 6;
  const int m = lane & 15, quad = lane >> 4;
  const int co0 = wave * 16;
  const float* Xb = X + (size_t)b * 256 * HW + p0;

  bf16x8 afr[8];
  const unsigned short* wrow = Wb + (co0 + m) * 256 + quad * 8;
  #pragma unroll
  for (int k = 0; k < 8; ++k) afr[k] = *(const bf16x8*)(wrow + k * 32);

  {
    const int px = tid & 63, rg = tid >> 6;
    float sq = 0.f;
    #pragma unroll
    for (int it = 0; it < 16; ++it) {
      int ci = rg * 64 + it * 4;
      float v0 = Xb[(size_t)(ci + 0) * HW + px];
      float v1 = Xb[(size_t)(ci + 1) * HW + px];
      float v2 = Xb[(size_t)(ci + 2) * HW + px];
      float v3 = Xb[(size_t)(ci + 3) * HW + px];
      sq += v0 * v0 + v1 * v1 + v2 * v2 + v3 * v3;
      *(uint2*)&bq[px * ST1 + ci] = make_uint2(pk2(v0, v1), pk2(v2, v3));
    }
    sqp[rg][px] = sq;
  }
  __syncthreads();
  if (tid < 64)
    ixn[tid] = 1.0f / (sqrtf(sqp[0][tid] + sqp[1][tid] + sqp[2][tid] + sqp[3][tid]) + 1e-6f);
  __syncthreads();

  f32x4 acc[4];
  #pragma unroll
  for (int nt = 0; nt < 4; ++nt) acc[nt] = (f32x4)0.f;
  #pragma unroll
  for (int nt = 0; nt < 4; ++nt) {
    const unsigned short* brow = &bq[(nt * 16 + m) * ST1 + quad * 8];
    #pragma unroll
    for (int k = 0; k < 8; ++k) {
      bf16x8 bfrag = *(const bf16x8*)(brow + k * 32);
      acc[nt] = MFMA16(afr[k], bfrag, acc[nt]);
    }
  }

  float s[4] = {0, 0, 0, 0}, q[4] = {0, 0, 0, 0};
  #pragma unroll
  for (int nt = 0; nt < 4; ++nt) {
    int px = nt * 16 + m;
    size_t bp = (size_t)b * HW + p0 + px;
    float ix = ixn[px];
    *(uint2*)&Y1[bp * 64 + co0 + quad * 4] =
        make_uint2(pk2(acc[nt][0], acc[nt][1]), pk2(acc[nt][2], acc[nt][3]));
    #pragma unroll
    for (int r = 0; r < 4; ++r) {
      int co = co0 + quad * 4 + r;
      float v = acc[nt][r];
      CS[((size_t)b * 64 + co) * HW + p0 + px] = f2bf(v * invwn[co] * ix);
      s[r] += v; q[r] = fmaf(v, v, q[r]);
    }
  }
  #pragma unroll
  for (int r = 0; r < 4; ++r) {
    float ss = s[r], qq = q[r];
    #pragma unroll
    for (int o = 8; o; o >>= 1) { ss += __shfl_xor(ss, o); qq += __shfl_xor(qq, o); }
    if (m == 0) {
      int co = co0 + quad * 4 + r;
      Sp[(size_t)co * NB1 + bid] = ss; Qp[(size_t)co * NB1 + bid] = qq;
    }
  }
#undef NB1
#undef ST1
}

// ---------------------------------------------------------------------------
// per-pixel sum over 64 ci of relu(bn1(y1))^2, y1 bf16 pixel-major. grid 196.
// ---------------------------------------------------------------------------
__global__ __launch_bounds__(256) void chansum_px(const unsigned short* __restrict__ Y1,
    const float* __restrict__ sc, const float* __restrict__ sh,
    float* __restrict__ part) {
  int g = blockIdx.x * 256 + threadIdx.x;
  const unsigned short* row = Y1 + (size_t)g * 64;
  float s = 0.f;
  #pragma unroll
  for (int j = 0; j < 8; ++j) {
    uint4 d = *(const uint4*)(row + j * 8);
    unsigned dd[4] = {d.x, d.y, d.z, d.w};
    #pragma unroll
    for (int e = 0; e < 4; ++e) {
      int c = j * 8 + e * 2;
      float v0 = fmaxf(0.f, fmaf(bf2f((unsigned short)(dd[e] & 0xffff)), sc[c], sh[c]));
      float v1 = fmaxf(0.f, fmaf(bf2f((unsigned short)(dd[e] >> 16)), sc[c + 1], sh[c + 1]));
      s = fmaf(v0, v0, s); s = fmaf(v1, v1, s);
    }
  }
  part[g] = s;
}

// 3x3 box-sum (zero pad) of part -> 1/(sqrt(.)+1e-6). grid 196
__global__ __launch_bounds__(256) void box3inv(const float* __restrict__ part,
                                               float* __restrict__ out) {
  int g = blockIdx.x * 256 + threadIdx.x;
  int b = g / HW, p = g - b * HW;
  int y = p / 56, x = p % 56;
  float tot = 0.f;
  for (int dy = -1; dy <= 1; dy++) {
    int yy = y + dy; if (yy < 0 || yy >= 56) continue;
    for (int dx = -1; dx <= 1; dx++) {
      int xx = x + dx; if (xx < 0 || xx >= 56) continue;
      tot += part[b * HW + yy * 56 + xx];
    }
  }
  out[g] = 1.0f / (sqrtf(tot) + 1e-6f);
}

// ---------------------------------------------------------------------------
// conv2: 3x3 64->64 pad1, implicit-GEMM MFMA. grid (56,16). CS bf16.
// ---------------------------------------------------------------------------
__global__ __launch_bounds__(256) void conv2_mfma(
    const unsigned short* __restrict__ Y1, const unsigned short* __restrict__ W2tb,
    const float* __restrict__ invwn, const float* __restrict__ ixn2,
    const float* __restrict__ sc1, const float* __restrict__ sh1,
    unsigned short* __restrict__ Y2, unsigned short* __restrict__ CS,
    float* __restrict__ Sp, float* __restrict__ Qp) {
#define STW 72
#define NB2 896
  __shared__ __align__(16) unsigned short ts[3 * 66 * STW];
  __shared__ float scl[64], shl[64];
  const int h = blockIdx.x, b = blockIdx.y;
  const int bid = b * 56 + h;
  const int tid = threadIdx.x;
  const int lane = tid & 63, wave = tid >> 6;
  const int m = lane & 15, quad = lane >> 4;
  const int co0 = wave * 16;
  if (tid < 64) { scl[tid] = sc1[tid]; shl[tid] = sh1[tid]; }

  bf16x8 afr[18];
  #pragma unroll
  for (int ks = 0; ks < 18; ++ks)
    afr[ks] = *(const bf16x8*)(W2tb + (co0 + m) * 576 + ks * 32 + quad * 8);
  __syncthreads();

  for (int l = tid; l < 6336; l += 256) {  // 3 rows x 66 cols x 32 ci-pairs
    int cp = l & 31, cc = (l >> 5) % 66, dy = l / 2112;
    int yy = h - 1 + dy, xx = cc - 1;
    unsigned pkv = 0u;
    if (yy >= 0 && yy < 56 && xx >= 0 && xx < 56) {
      unsigned d = *(const unsigned*)&Y1[((size_t)b * HW + yy * 56 + xx) * 64 + cp * 2];
      float v0 = bf2f((unsigned short)(d & 0xffff));
      float v1 = bf2f((unsigned short)(d >> 16));
      v0 = fmaxf(0.f, fmaf(v0, scl[cp * 2], shl[cp * 2]));
      v1 = fmaxf(0.f, fmaf(v1, scl[cp * 2 + 1], shl[cp * 2 + 1]));
      pkv = pk2(v0, v1);
    }
    *(unsigned*)&ts[(dy * 66 + cc) * STW + cp * 2] = pkv;
  }
  __syncthreads();

  f32x4 acc[4];
  #pragma unroll
  for (int nt = 0; nt < 4; ++nt) acc[nt] = (f32x4)0.f;
  #pragma unroll
  for (int nt = 0; nt < 4; ++nt) {
    #pragma unroll
    for (int ks = 0; ks < 18; ++ks) {
      int tap = ks >> 1, half = ks & 1;
      int dy = tap / 3, dx = tap % 3;
      bf16x8 bfrag = *(const bf16x8*)&ts[(dy * 66 + nt * 16 + m + dx) * STW + half * 32 + quad * 8];
      acc[nt] = MFMA16(afr[ks], bfrag, acc[nt]);
    }
  }

  float s[4] = {0, 0, 0, 0}, q[4] = {0, 0, 0, 0};
  #pragma unroll
  for (int nt = 0; nt < 4; ++nt) {
    int px = nt * 16 + m;
    bool valid = px < 56;
    int pix = h * 56 + px;
    if (valid) {
      float ix = ixn2[b * HW + pix];
      size_t bp = (size_t)b * HW + pix;
      *(uint2*)&Y2[bp * 64 + co0 + quad * 4] =
          make_uint2(pk2(acc[nt][0], acc[nt][1]), pk2(acc[nt][2], acc[nt][3]));
      #pragma unroll
      for (int r = 0; r < 4; ++r) {
        int co = co0 + quad * 4 + r;
        CS[((size_t)b * 64 + co) * HW + pix] = f2bf(acc[nt][r] * invwn[co] * ix);
      }
    }
    #pragma unroll
    for (int r = 0; r < 4; ++r) {
      float v = valid ? acc[nt][r] : 0.f;
      s[r] += v; q[r] = fmaf(v, v, q[r]);
    }
  }
  #pragma unroll
  for (int r = 0; r < 4; ++r) {
    float ss = s[r], qq = q[r];
    #pragma unroll
    for (int o = 8; o; o >>= 1) { ss += __shfl_xor(ss, o); qq += __shfl_xor(qq, o); }
    if (m == 0) {
      int co = co0 + quad * 4 + r;
      Sp[(size_t)co * NB2 + bid] = ss; Qp[(size_t)co * NB2 + bid] = qq;
    }
  }
#undef NB2
#undef STW
}

// ---------------------------------------------------------------------------
// conv3: 1x1 64->256 MFMA. grid (49,16). Outputs y3 bf16 + cos3 bf16.
// ---------------------------------------------------------------------------
__global__ __launch_bounds__(256) void conv3_mfma(
    const unsigned short* __restrict__ Y2, const unsigned short* __restrict__ W3b,
    const float* __restrict__ invwn,
    const float* __restrict__ sc2, const float* __restrict__ sh2,
    unsigned short* __restrict__ Y3, unsigned short* __restrict__ CS,
    float* __restrict__ Sp, float* __restrict__ Qp) {
#define ST3 72
#define NB3 784
  __shared__ __align__(16) unsigned short bq[64 * ST3];
  __shared__ float scl[64], shl[64], sqp[4][64], ixn[64];
  const int p0 = blockIdx.x * 64, b = blockIdx.y;
  const int bid = b * 49 + blockIdx.x;
  const int tid = threadIdx.x;
  const int lane = tid & 63, wave = tid >> 6;
  const int m = lane & 15, quad = lane >> 4;
  const int co0 = wave * 64;
  if (tid < 64) { scl[tid] = sc2[tid]; shl[tid] = sh2[tid]; }

  bf16x8 afr[4][2];
  #pragma unroll
  for (int mt = 0; mt < 4; ++mt)
    #pragma unroll
    for (int k = 0; k < 2; ++k)
      afr[mt][k] = *(const bf16x8*)(W3b + (co0 + mt * 16 + m) * 64 + k * 32 + quad * 8);
  __syncthreads();

  {
    const int cp = tid & 31, pxg = tid >> 5;
    #pragma unroll
    for (int it = 0; it < 8; ++it) {
      int px = pxg * 8 + it;
      unsigned d = *(const unsigned*)&Y2[((size_t)b * HW + p0 + px) * 64 + cp * 2];
      float v0 = bf2f((unsigned short)(d & 0xffff));
      float v1 = bf2f((unsigned short)(d >> 16));
      v0 = fmaxf(0.f, fmaf(v0, scl[cp * 2], shl[cp * 2]));
      v1 = fmaxf(0.f, fmaf(v1, scl[cp * 2 + 1], shl[cp * 2 + 1]));
      *(unsigned*)&bq[px * ST3 + cp * 2] = pk2(v0, v1);
    }
  }
  __syncthreads();
  {
    const int px = tid & 63, hh = tid >> 6;
    const unsigned short* row = &bq[px * ST3 + hh * 16];
    float sq = 0.f;
    #pragma unroll
    for (int e = 0; e < 16; ++e) { float v = bf2f(row[e]); sq = fmaf(v, v, sq); }
    sqp[hh][px] = sq;
  }
  __syncthreads();
  if (tid < 64)
    ixn[tid] = 1.0f / (sqrtf(sqp[0][tid] + sqp[1][tid] + sqp[2][tid] + sqp[3][tid]) + 1e-6f);
  __syncthreads();

  f32x4 acc[4][4];
  #pragma unroll
  for (int mt = 0; mt < 4; ++mt)
    #pragma unroll
    for (int nt = 0; nt < 4; ++nt) acc[mt][nt] = (f32x4)0.f;
  #pragma unroll
  for (int nt = 0; nt < 4; ++nt) {
    const unsigned short* brow = &bq[(nt * 16 + m) * ST3 + quad * 8];
    bf16x8 b0 = *(const bf16x8*)(brow);
    bf16x8 b1 = *(const bf16x8*)(brow + 32);
    #pragma unroll
    for (int mt = 0; mt < 4; ++mt) {
      acc[mt][nt] = MFMA16(afr[mt][0], b0, acc[mt][nt]);
      acc[mt][nt] = MFMA16(afr[mt][1], b1, acc[mt][nt]);
    }
  }

  #pragma unroll
  for (int mt = 0; mt < 4; ++mt) {
    float s[4] = {0, 0, 0, 0}, q[4] = {0, 0, 0, 0};
    #pragma unroll
    for (int nt = 0; nt < 4; ++nt) {
      int px = nt * 16 + m;
      float ix = ixn[px];
      #pragma unroll
      for (int r = 0; r < 4; ++r) {
        int co = co0 + mt * 16 + quad * 4 + r;
        float v = acc[mt][nt][r];
        size_t off = ((size_t)b * 256 + co) * HW + p0 + px;
        Y3[off] = f2bf(v);
        CS[off] = f2bf(v * invwn[co] * ix);
        s[r] += v; q[r] = fmaf(v, v, q[r]);
      }
    }
    #pragma unroll
    for (int r = 0; r < 4; ++r) {
      float ss = s[r], qq = q[r];
      #pragma unroll
      for (int o = 8; o; o >>= 1) { ss += __shfl_xor(ss, o); qq += __shfl_xor(qq, o); }
      if (m == 0) {
        int co = co0 + mt * 16 + quad * 4 + r;
        Sp[(size_t)co * NB3 + bid] = ss; Qp[(size_t)co * NB3 + bid] = qq;
      }
    }
  }
#undef NB3
#undef ST3
}

// ---------------------------------------------------------------------------
// sample5: one block per cell-pair (u, u+BC/2), ALL 5 samples per cell.
// Counter identities (sC = BC*HW, halfn = 2.5*sC, eU = u*HW+p, eV = eU+sC/2):
//   u: s0,s1,s2 = o0(eU+t*sC); s3 = o1(eV), s4 = o1(eV+sC)
//   v: s0,s1    = o0(eV+t*sC); s2 = o1(eU), s3 = o1(eU+sC), s4 = o1(eU+2sC)
// Winner selection via uint-key argmin: score = (-ln u)*exp(-logit) > 0 is
// uint-monotone in its float bits; key = (bits & ~0xFFF) | p -> v_min_u32.
// ---------------------------------------------------------------------------
template <int NT>
__global__ __launch_bounds__(NT) void sample5_k(const unsigned short* __restrict__ CS,
    float* __restrict__ acc, uint32_t key0, uint32_t key1, int BC, float scale) {
  const int u = blockIdx.x;
  const int v = u + (BC >> 1);
  const uint32_t sC = (uint32_t)BC * (uint32_t)HW;
  const uint32_t halfn = sC * 2u + (sC >> 1);
  const unsigned short* rowU = CS + (size_t)u * HW;
  const unsigned short* rowV = CS + (size_t)v * HW;
  const int tid = threadIdx.x;
  const int lane = tid & 63;

  __shared__ unsigned kmin[10];
  __shared__ float wsum[10];
  if (tid < 10) { kmin[tid] = 0xFFFFFFFFu; wsum[tid] = 0.f; }

  unsigned bk[10];
  #pragma unroll
  for (int k = 0; k < 10; ++k) bk[k] = 0xFFFFFFFFu;

  const uint32_t baseU0 = (uint32_t)u * (uint32_t)HW;
  const uint32_t baseV0 = (uint32_t)v * (uint32_t)HW;
  for (int p = tid; p < HW; p += NT) {
    float wu = __builtin_amdgcn_exp2f(bf2f(rowU[p]) * NEG2LOG2E);  // exp(-2c)
    float wv = __builtin_amdgcn_exp2f(bf2f(rowV[p]) * NEG2LOG2E);
    uint32_t eU = baseU0 + (uint32_t)p;
    uint32_t eV = baseV0 + (uint32_t)p;
    uint32_t xa[5] = {eU, eU + sC, eU + 2 * sC, eV, eV + sC};
    uint32_t xb[5] = {eU + halfn, eU + sC + halfn, eU + 2 * sC + halfn,
                      eV + halfn, eV + sC + halfn};
    uint32_t oa[5], ob[5];
    threefry5(key0, key1, xa, xb, oa, ob);
    uint32_t wds[10] = {oa[0], oa[1], oa[2], ob[3], ob[4],   // u s0..s4
                        oa[3], oa[4], ob[0], ob[1], ob[2]};  // v s0..s4
    #pragma unroll
    for (int k = 0; k < 10; ++k) {
      float s = exp_draw(wds[k]) * (k < 5 ? wu : wv);
      unsigned key = (__float_as_uint(s) & 0xFFFFF000u) | (unsigned)p;
      bk[k] = bk[k] < key ? bk[k] : key;
    }
  }

  __syncthreads();  // kmin/wsum init visible
  #pragma unroll
  for (int k = 0; k < 10; ++k) {
    unsigned kv = bk[k];
    #pragma unroll
    for (int o = 32; o; o >>= 1) {
      unsigned ov = __shfl_xor(kv, o);
      kv = kv < ov ? kv : ov;
    }
    if (lane == 0) atomicMin(&kmin[k], kv);
  }
  __syncthreads();

  // 11x11 zero-padded window sums around the 10 winners
  for (int idx = tid; idx < 1210; idx += NT) {
    int win = idx / 121, j = idx - win * 121;
    int bidx = (int)(kmin[win] & 0xFFFu);
    int py = bidx / 56, px = bidx % 56;
    int yy = py + j / 11 - 5, xx = px + j % 11 - 5;
    if (yy >= 0 && yy < 56 && xx >= 0 && xx < 56) {
      const unsigned short* row = (win < 5) ? rowU : rowV;
      atomicAdd(&wsum[win], bf2f(row[yy * 56 + xx]));
    }
  }
  __syncthreads();
  if (tid == 0) {
    float t = 0.f;
    #pragma unroll
    for (int k = 0; k < 10; ++k) t += wsum[k];
    atomicAdd(acc, t * scale);
  }
}

// ---------------------------------------------------------------------------
// out = relu(bn3(y3) + x), y3 bf16; emits acc scalar at out[12845056]
// ---------------------------------------------------------------------------
__global__ __launch_bounds__(256) void final_k(const unsigned short* __restrict__ Y3,
    const float* __restrict__ X, const float* __restrict__ sc,
    const float* __restrict__ sh, const float* __restrict__ acc,
    float* __restrict__ out) {
  size_t i4 = (size_t)blockIdx.x * 256 + threadIdx.x;
  if (i4 == 0) out[12845056] = acc[0];
  size_t i = i4 * 4;
  int c = (int)((i / HW) % 256);
  float a = sc[c], d = sh[c];
  uint2 yd = *(const uint2*)&Y3[i];
  float4 xv = *(const float4*)&X[i];
  float4 r;
  r.x = fmaxf(0.f, fmaf(bf2f((unsigned short)(yd.x & 0xffff)), a, d) + xv.x);
  r.y = fmaxf(0.f, fmaf(bf2f((unsigned short)(yd.x >> 16)),    a, d) + xv.y);
  r.z = fmaxf(0.f, fmaf(bf2f((unsigned short)(yd.y & 0xffff)), a, d) + xv.z);
  r.w = fmaxf(0.f, fmaf(bf2f((unsigned short)(yd.y >> 16)),    a, d) + xv.w);
  *(float4*)&out[i] = r;
}

// ---------------------------------------------------------------------------
extern "C" void kernel_launch(void* const* d_in, const int* in_sizes, int n_in,
                              void* d_out, int out_size, void* d_ws, size_t ws_size,
                              hipStream_t stream) {
  (void)in_sizes; (void)n_in; (void)out_size; (void)ws_size;
  const float* x  = (const float*)d_in[0];
  const float* w1 = (const float*)d_in[1];
  const float* w2 = (const float*)d_in[2];
  const float* w3 = (const float*)d_in[3];
  const float* g1 = (const float*)d_in[4];
  const float* b1 = (const float*)d_in[5];
  const float* g2 = (const float*)d_in[6];
  const float* b2 = (const float*)d_in[7];
  const float* g3 = (const float*)d_in[8];
  const float* b3 = (const float*)d_in[9];
  float* out = (float*)d_out;
  float* ws = (float*)d_ws;

  // workspace layout (float units; bf16 buffers use elems/2 float units)
  size_t o = 0;
  unsigned short* y3b  = (unsigned short*)(ws + o); o += 6422528;  // 12845056 bf16
  unsigned short* cos3 = (unsigned short*)(ws + o); o += 6422528;  // 12845056 bf16
  unsigned short* CSb  = (unsigned short*)(ws + o); o += 1605632;  // 3211264 bf16
  unsigned short* y1b  = (unsigned short*)(ws + o); o += 1605632;  // 3211264 bf16
  unsigned short* y2b  = (unsigned short*)(ws + o); o += 1605632;  // 3211264 bf16
  unsigned short* W1b  = (unsigned short*)(ws + o); o += 8192;     // 16384 bf16
  unsigned short* W2tb = (unsigned short*)(ws + o); o += 18432;    // 36864 bf16
  unsigned short* W3b  = (unsigned short*)(ws + o); o += 8192;     // 16384 bf16
  float* part = ws + o; o += NPIX;
  float* ixn2 = ws + o; o += NPIX;
  float* invwn = ws + o; o += 384;
  float* Sp1 = ws + o; o += 64 * 784;   float* Qp1 = ws + o; o += 64 * 784;
  float* Sp2 = ws + o; o += 64 * 896;   float* Qp2 = ws + o; o += 64 * 896;
  float* Sp3 = ws + o; o += 256 * 784;  float* Qp3 = ws + o; o += 256 * 784;
  float* acc = ws + o; o += 1;
  float* sc1 = ws + o; o += 64;  float* sh1 = ws + o; o += 64;
  float* sc2 = ws + o; o += 64;  float* sh2 = ws + o; o += 64;
  float* sc3 = ws + o; o += 256; float* sh3 = ws + o; o += 256;

  hipMemsetAsync(acc, 0, sizeof(float), stream);

  // JAX: k0,k1,k2 = split(key(42), 3); (Ai,Bi) = threefry2x32((0,42),(i,i+3))
  uint32_t A0, B0, A1, B1, A2, B2;
  threefry2x32(0u, 42u, 0u, 3u, A0, B0);
  threefry2x32(0u, 42u, 1u, 4u, A1, B1);
  threefry2x32(0u, 42u, 2u, 5u, A2, B2);

  const float scale64  = 1.0f / (121.0f * 5.0f * 1024.0f);
  const float scale256 = 1.0f / (121.0f * 5.0f * 4096.0f);

  wprep_k<<<274, 256, 0, stream>>>(w1, w2, w3, invwn, W1b, W2tb, W3b);

  // stage 1: 1x1 conv 256->64 (MFMA) + BN1 partials
  conv1_mfma<<<dim3(49, 16), 256, 0, stream>>>(x, W1b, invwn, y1b, CSb, Sp1, Qp1);
  bn_fin<<<64, 256, 0, stream>>>(Sp1, Qp1, g1, b1, sc1, sh1, 784);
  sample5_k<512><<<512, 512, 0, stream>>>(CSb, acc, A0, A1, 1024, scale64);

  // stage 2: 3x3 conv 64->64 pad 1 (MFMA), t1 = relu(bn1(y1)) inline
  chansum_px<<<196, 256, 0, stream>>>(y1b, sc1, sh1, part);
  box3inv<<<196, 256, 0, stream>>>(part, ixn2);
  conv2_mfma<<<dim3(56, 16), 256, 0, stream>>>(
      y1b, W2tb, invwn + 64, ixn2, sc1, sh1, y2b, CSb, Sp2, Qp2);
  bn_fin<<<64, 256, 0, stream>>>(Sp2, Qp2, g2, b2, sc2, sh2, 896);
  sample5_k<512><<<512, 512, 0, stream>>>(CSb, acc, A2, B0, 1024, scale64);

  // stage 3: 1x1 conv 64->256 (MFMA), t2 = relu(bn2(y2)) inline
  conv3_mfma<<<dim3(49, 16), 256, 0, stream>>>(
      y2b, W3b, invwn + 128, sc2, sh2, y3b, cos3, Sp3, Qp3);
  bn_fin<<<256, 256, 0, stream>>>(Sp3, Qp3, g3, b3, sc3, sh3, 784);
  sample5_k<256><<<2048, 256, 0, stream>>>(cos3, acc, B1, B2, 4096, scale256);
  final_k<<<12544, 256, 0, stream>>>(y3b, x, sc3, sh3, acc, out);
}